// Round 19
// baseline (62.612 us; speedup 1.0000x reference)
//
#include <hip/hip_runtime.h>

typedef __attribute__((ext_vector_type(4))) int   i32x4;
typedef __attribute__((ext_vector_type(4))) float f32x4;

#define HDIM 16
#define MDIM 2048
#define NDIM 2048
#define KDIM 128

// Pack 4 int32 (values 0..126, high bytes zero) into one dword of 4 int8.
__device__ inline int pack4(i32x4 v) {
    return v.x | (v.y << 8) | (v.z << 16) | (v.w << 24);
}

// ---------------------------------------------------------------------------
// Prep v4 — r18's XCD-aligned fragment-linear re-layout, now with
// NON-TEMPORAL READS of the int32 inputs: A/B are read exactly once
// (zero reuse), so bypassing L2 on the read stream reserves each XCD's
// 4 MB L2 for the freshly-packed output slabs (4.2 MB/XCD) — they survive
// until the GEMM consumes them (the GEMM's NT stores, r18, then keep them
// resident through the GEMM phase too).
//
// 2048 blocks x 256 thr; block handles a 32-row slab; XCD k packs exactly
// the slabs its own GEMM blocks (h=2k,2k+1) will read.
//   read : thread t NT-packs 16 int32 (64 B contiguous) at row t>>3,
//          col (t&7)*16 -> 1x ds_write_b128 (lds[32][36], bank-floor).
//   write: thread t emits 16 B at dst + s*4096 + t*16 (dense 4 KB run),
//          sourced from lds[(t>>7)*16 + (t&15)][(((t>>6)&1)*4+((t>>4)&3))*4]
//          — matches the GEMM's rowgrp*2048 + ks*1024 + lane*16 exactly.
// Blocks i<128 also copy the scale_out passthrough tail.
// ---------------------------------------------------------------------------
__global__ __launch_bounds__(256)
void prep_relayout(const int* __restrict__ A,
                   const int* __restrict__ B,
                   const float* __restrict__ sO,
                   unsigned char* __restrict__ A8T,
                   unsigned char* __restrict__ B8T,
                   float* __restrict__ out_tail) {
    __shared__ int lds[32][36];

    const int i = blockIdx.x;
    const int t = threadIdx.x;

    // XCD-aligned chunked swizzle: XCD k = i&7 owns chunk u = i>>3 (0..255);
    // u<128 -> A slab 128k+u, else B slab 128k+(u-128).
    const int k = i & 7;
    const int u = i >> 3;
    const bool isB = (u >= 128);
    const int s = 128 * k + (isB ? (u - 128) : u);   // 32-row slab id 0..1023
    const int* __restrict__ src = isB ? B : A;
    unsigned char* __restrict__ dst = isB ? B8T : A8T;

    if (i < 128) out_tail[i * 256 + t] = sO[i * 256 + t];

    // ---- read + pack: 64 B contiguous per thread, NT (read-once) ----
    const int r = t >> 3;          // 0..31 slab row
    const int q = t & 7;           // 16-int column chunk
    const i32x4* p = reinterpret_cast<const i32x4*>(
        src + (((size_t)s * 32 + r) * 128 + q * 16));
    i32x4 v0 = __builtin_nontemporal_load(p);
    i32x4 v1 = __builtin_nontemporal_load(p + 1);
    i32x4 v2 = __builtin_nontemporal_load(p + 2);
    i32x4 v3 = __builtin_nontemporal_load(p + 3);
    *reinterpret_cast<i32x4*>(&lds[r][q * 4]) =
        (i32x4){pack4(v0), pack4(v1), pack4(v2), pack4(v3)};
    __syncthreads();

    // ---- fragment-linear write: one dense 4 KB block run ----
    const int fr = t & 15, kg = (t >> 4) & 3, ks = (t >> 6) & 1, rg = t >> 7;
    const int cc = ks * 4 + kg;
    *reinterpret_cast<i32x4*>(dst + (size_t)s * 4096 + t * 16) =
        *reinterpret_cast<const i32x4*>(&lds[rg * 16 + fr][cc * 4]);
}

// ---------------------------------------------------------------------------
// Batched i8 GEMM (r18-proven, unchanged): fragment-linear 1 KB burst loads
// + LDS-transpose epilogue -> dense 1 KB row-linear NT store runs (full
// 128-B lines, no RMW; write stream bypasses L2, packed inputs stay hot).
// Tile 128x256, 512 thr = 8 waves 2x4, wave = 64x64 via 4x4 fragments of
// v_mfma_i32_16x16x64_i8, SWAPPED operands (lane fr=lane&15, kg=lane>>4
// holds C[m=..+fr][n=..+kg*4+r]). Grid 2048, chunked XCD swizzle.
// Epilogue math (bit-exact): c = clamp(rint(acc*((sA[m]/sO[m])*sB[n])),
// -127, 127), stored as float32.
// ---------------------------------------------------------------------------
__global__ __launch_bounds__(512)
void gemm_i8_fused(const unsigned char* __restrict__ A8T,
                   const unsigned char* __restrict__ B8T,
                   const float* __restrict__ sA,
                   const float* __restrict__ sB,
                   const float* __restrict__ sO,
                   float* __restrict__ out) {
    __shared__ float lout[32 * 256];   // 32 KB epilogue staging

    // chunked XCD swizzle: nwg = 2048, 8 XCDs, 256 per chunk
    const int i = blockIdx.x;
    const int w = (i & 7) * 256 + (i >> 3);
    const int bx = w & 7;            // 8 col-tiles of 256
    const int by = (w >> 3) & 15;    // 16 row-tiles of 128
    const int h  = w >> 7;

    const int bm = by * 128;
    const int bn = bx * 256;
    const int tid  = threadIdx.x;
    const int wave = tid >> 6;
    const int lane = tid & 63;
    const int wm = (wave >> 2) * 64;   // 2 wave-rows of 64
    const int wn = (wave & 3) * 64;    // 4 wave-cols of 64
    const int fr = lane & 15;          // out row m sub-index
    const int kg = lane >> 4;          // out n-subchunk

    const unsigned char* AhT = A8T + (size_t)h * MDIM * KDIM;
    const unsigned char* BhT = B8T + (size_t)h * NDIM * KDIM;
    const int abase = (bm + wm) >> 4;  // rowgroup base for this wave's A rows
    const int bbase = (bn + wn) >> 4;  // rowgroup base for this wave's B rows

    i32x4 acc[4][4];
#pragma unroll
    for (int mi = 0; mi < 4; ++mi)
#pragma unroll
        for (int ni = 0; ni < 4; ++ni)
            acc[mi][ni] = (i32x4){0, 0, 0, 0};

#pragma unroll
    for (int ks = 0; ks < 2; ++ks) {
        i32x4 af[4], bf[4];
#pragma unroll
        for (int mi = 0; mi < 4; ++mi)
            af[mi] = *reinterpret_cast<const i32x4*>(
                AhT + (size_t)(abase + mi) * 2048 + ks * 1024 + lane * 16);
#pragma unroll
        for (int ni = 0; ni < 4; ++ni)
            bf[ni] = *reinterpret_cast<const i32x4*>(
                BhT + (size_t)(bbase + ni) * 2048 + ks * 1024 + lane * 16);
#pragma unroll
        for (int mi = 0; mi < 4; ++mi)
#pragma unroll
            for (int ni = 0; ni < 4; ++ni)
                acc[mi][ni] = __builtin_amdgcn_mfma_i32_16x16x64_i8(
                    bf[ni], af[mi], acc[mi][ni], 0, 0, 0);  // swapped -> C^T frag
    }

    // Scales (bit-exact reference op order).
    const float* sAh = sA + h * MDIM;
    const float* sBh = sB + h * NDIM;
    const float* sOh = sO + h * MDIM;

    float smv[4];
#pragma unroll
    for (int mi = 0; mi < 4; ++mi) {
        const int m = bm + wm + mi * 16 + fr;
        smv[mi] = sAh[m] / sOh[m];
    }
    f32x4 sbv[4];
#pragma unroll
    for (int ni = 0; ni < 4; ++ni)
        sbv[ni] = *reinterpret_cast<const f32x4*>(sBh + bn + wn + ni * 16 + kg * 4);

    // LDS-transpose epilogue: 4 phases (mi), fully unrolled.
    const int lrow = ((wave >> 2) << 4) + fr;     // 0..31 staging row
    char* lbase = reinterpret_cast<char*>(lout);
#pragma unroll
    for (int p = 0; p < 4; ++p) {
        // -- write: wave's scaled 16x64 sub-tile for mi=p --
#pragma unroll
        for (int ni = 0; ni < 4; ++ni) {
            f32x4 o;
#pragma unroll
            for (int r = 0; r < 4; ++r) {
                float c = (float)acc[p][ni][r] * (smv[p] * sbv[ni][r]);
                float rv = rintf(c);                       // RNE == np.round
                o[r] = fminf(fmaxf(rv, -127.0f), 127.0f);
            }
            const int colb = (wn + ni * 16 + kg * 4) * 4;  // byte col in row
            *reinterpret_cast<f32x4*>(
                lbase + lrow * 1024 + (colb ^ ((lrow & 7) << 4))) = o;
        }
        __syncthreads();
        // -- read row-linear + dense 1 KB NT wave stores (full lines) --
#pragma unroll
        for (int j = 0; j < 4; ++j) {
            const int idx = j * 512 + tid;        // 0..2047 16B-chunks
            const int r2  = idx >> 6;             // staging row 0..31
            const int c16 = idx & 63;             // 16B chunk in row
            f32x4 v = *reinterpret_cast<const f32x4*>(
                lbase + r2 * 1024 + ((c16 * 16) ^ ((r2 & 7) << 4)));
            const int grow = bm + ((r2 >> 4) * 64) + p * 16 + (r2 & 15);
            __builtin_nontemporal_store(v, reinterpret_cast<f32x4*>(
                out + ((size_t)h * MDIM + grow) * NDIM + bn + c16 * 4));
        }
        __syncthreads();
    }
}

extern "C" void kernel_launch(void* const* d_in, const int* in_sizes, int n_in,
                              void* d_out, int out_size, void* d_ws, size_t ws_size,
                              hipStream_t stream) {
    const int*   A  = (const int*)d_in[0];
    const int*   B  = (const int*)d_in[1];
    const float* sA = (const float*)d_in[2];
    const float* sB = (const float*)d_in[3];
    const float* sO = (const float*)d_in[4];
    float* out = (float*)d_out;

    unsigned char* A8T = (unsigned char*)d_ws;
    unsigned char* B8T = A8T + (size_t)HDIM * MDIM * KDIM;

    prep_relayout<<<2048, 256, 0, stream>>>(
        A, B, sO, A8T, B8T, out + (size_t)HDIM * MDIM * NDIM);

    gemm_i8_fused<<<2048, 512, 0, stream>>>(A8T, B8T, sA, sB, sO, out);
}

// Round 20
// 59.070 us; speedup vs baseline: 1.0600x; 1.0600x over previous
//
#include <hip/hip_runtime.h>

typedef __attribute__((ext_vector_type(4))) int   i32x4;
typedef __attribute__((ext_vector_type(4))) float f32x4;

#define HDIM 16
#define MDIM 2048
#define NDIM 2048
#define KDIM 128

// Pack 4 int32 (values 0..126, high bytes zero) into one dword of 4 int8.
__device__ inline int pack4(i32x4 v) {
    return v.x | (v.y << 8) | (v.z << 16) | (v.w << 24);
}

// ---------------------------------------------------------------------------
// Prep (r18-proven, NT-load experiment reverted — r19 measured NT reads
// -3.4 us: NT forfeits the cache request-merge path on read-once streams;
// NT belongs on the STORE stream only).
//
// XCD-aligned fragment-linear re-layout: with the chunked swizzle, XCD k
// packs exactly the A/B slabs ([128k,128k+128) each) that its own GEMM
// blocks (h=2k,2k+1) read. Packed data is born in the consuming XCD's L2
// and stays resident (GEMM's NT stores don't evict it).
//
// 2048 blocks x 256 thr; block handles a 32-row slab.
//   read : thread t packs 16 int32 (64 B contiguous, 4x dwordx4) at
//          row t>>3, col (t&7)*16 -> 1x ds_write_b128 (lds[32][36]).
//   write: thread t emits 16 B at dst + s*4096 + t*16 (dense 4 KB run),
//          sourced from lds[(t>>7)*16 + (t&15)][(((t>>6)&1)*4+((t>>4)&3))*4]
//          — matches the GEMM's rowgrp*2048 + ks*1024 + lane*16 exactly.
// Blocks i<128 also copy the scale_out passthrough tail.
// ---------------------------------------------------------------------------
__global__ __launch_bounds__(256)
void prep_relayout(const int* __restrict__ A,
                   const int* __restrict__ B,
                   const float* __restrict__ sO,
                   unsigned char* __restrict__ A8T,
                   unsigned char* __restrict__ B8T,
                   float* __restrict__ out_tail) {
    __shared__ int lds[32][36];

    const int i = blockIdx.x;
    const int t = threadIdx.x;

    // XCD-aligned chunked swizzle: XCD k = i&7 owns chunk u = i>>3 (0..255);
    // u<128 -> A slab 128k+u, else B slab 128k+(u-128).
    const int k = i & 7;
    const int u = i >> 3;
    const bool isB = (u >= 128);
    const int s = 128 * k + (isB ? (u - 128) : u);   // 32-row slab id 0..1023
    const int* __restrict__ src = isB ? B : A;
    unsigned char* __restrict__ dst = isB ? B8T : A8T;

    if (i < 128) out_tail[i * 256 + t] = sO[i * 256 + t];

    // ---- read + pack: 64 B contiguous per thread ----
    const int r = t >> 3;          // 0..31 slab row
    const int q = t & 7;           // 16-int column chunk
    const i32x4* p = reinterpret_cast<const i32x4*>(
        src + (((size_t)s * 32 + r) * 128 + q * 16));
    i32x4 v0 = p[0], v1 = p[1], v2 = p[2], v3 = p[3];
    *reinterpret_cast<i32x4*>(&lds[r][q * 4]) =
        (i32x4){pack4(v0), pack4(v1), pack4(v2), pack4(v3)};
    __syncthreads();

    // ---- fragment-linear write: one dense 4 KB block run ----
    const int fr = t & 15, kg = (t >> 4) & 3, ks = (t >> 6) & 1, rg = t >> 7;
    const int cc = ks * 4 + kg;
    *reinterpret_cast<i32x4*>(dst + (size_t)s * 4096 + t * 16) =
        *reinterpret_cast<const i32x4*>(&lds[rg * 16 + fr][cc * 4]);
}

// ---------------------------------------------------------------------------
// Batched i8 GEMM (r18-proven): fragment-linear 1 KB burst loads +
// LDS-transpose epilogue -> dense 1 KB row-linear NT store runs (full
// 128-B lines, no RMW; write stream bypasses L2, packed inputs stay hot).
// Tile 128x256, 512 thr = 8 waves 2x4, wave = 64x64 via 4x4 fragments of
// v_mfma_i32_16x16x64_i8, SWAPPED operands (lane fr=lane&15, kg=lane>>4
// holds C[m=..+fr][n=..+kg*4+r]). Grid 2048, chunked XCD swizzle.
// Epilogue math (bit-exact): c = clamp(rint(acc*((sA[m]/sO[m])*sB[n])),
// -127, 127), stored as float32.
// ---------------------------------------------------------------------------
__global__ __launch_bounds__(512)
void gemm_i8_fused(const unsigned char* __restrict__ A8T,
                   const unsigned char* __restrict__ B8T,
                   const float* __restrict__ sA,
                   const float* __restrict__ sB,
                   const float* __restrict__ sO,
                   float* __restrict__ out) {
    __shared__ float lout[32 * 256];   // 32 KB epilogue staging

    // chunked XCD swizzle: nwg = 2048, 8 XCDs, 256 per chunk
    const int i = blockIdx.x;
    const int w = (i & 7) * 256 + (i >> 3);
    const int bx = w & 7;            // 8 col-tiles of 256
    const int by = (w >> 3) & 15;    // 16 row-tiles of 128
    const int h  = w >> 7;

    const int bm = by * 128;
    const int bn = bx * 256;
    const int tid  = threadIdx.x;
    const int wave = tid >> 6;
    const int lane = tid & 63;
    const int wm = (wave >> 2) * 64;   // 2 wave-rows of 64
    const int wn = (wave & 3) * 64;    // 4 wave-cols of 64
    const int fr = lane & 15;          // out row m sub-index
    const int kg = lane >> 4;          // out n-subchunk

    const unsigned char* AhT = A8T + (size_t)h * MDIM * KDIM;
    const unsigned char* BhT = B8T + (size_t)h * NDIM * KDIM;
    const int abase = (bm + wm) >> 4;  // rowgroup base for this wave's A rows
    const int bbase = (bn + wn) >> 4;  // rowgroup base for this wave's B rows

    i32x4 acc[4][4];
#pragma unroll
    for (int mi = 0; mi < 4; ++mi)
#pragma unroll
        for (int ni = 0; ni < 4; ++ni)
            acc[mi][ni] = (i32x4){0, 0, 0, 0};

#pragma unroll
    for (int ks = 0; ks < 2; ++ks) {
        i32x4 af[4], bf[4];
#pragma unroll
        for (int mi = 0; mi < 4; ++mi)
            af[mi] = *reinterpret_cast<const i32x4*>(
                AhT + (size_t)(abase + mi) * 2048 + ks * 1024 + lane * 16);
#pragma unroll
        for (int ni = 0; ni < 4; ++ni)
            bf[ni] = *reinterpret_cast<const i32x4*>(
                BhT + (size_t)(bbase + ni) * 2048 + ks * 1024 + lane * 16);
#pragma unroll
        for (int mi = 0; mi < 4; ++mi)
#pragma unroll
            for (int ni = 0; ni < 4; ++ni)
                acc[mi][ni] = __builtin_amdgcn_mfma_i32_16x16x64_i8(
                    bf[ni], af[mi], acc[mi][ni], 0, 0, 0);  // swapped -> C^T frag
    }

    // Scales (bit-exact reference op order).
    const float* sAh = sA + h * MDIM;
    const float* sBh = sB + h * NDIM;
    const float* sOh = sO + h * MDIM;

    float smv[4];
#pragma unroll
    for (int mi = 0; mi < 4; ++mi) {
        const int m = bm + wm + mi * 16 + fr;
        smv[mi] = sAh[m] / sOh[m];
    }
    f32x4 sbv[4];
#pragma unroll
    for (int ni = 0; ni < 4; ++ni)
        sbv[ni] = *reinterpret_cast<const f32x4*>(sBh + bn + wn + ni * 16 + kg * 4);

    // LDS-transpose epilogue: 4 phases (mi), fully unrolled.
    const int lrow = ((wave >> 2) << 4) + fr;     // 0..31 staging row
    char* lbase = reinterpret_cast<char*>(lout);
#pragma unroll
    for (int p = 0; p < 4; ++p) {
        // -- write: wave's scaled 16x64 sub-tile for mi=p --
#pragma unroll
        for (int ni = 0; ni < 4; ++ni) {
            f32x4 o;
#pragma unroll
            for (int r = 0; r < 4; ++r) {
                float c = (float)acc[p][ni][r] * (smv[p] * sbv[ni][r]);
                float rv = rintf(c);                       // RNE == np.round
                o[r] = fminf(fmaxf(rv, -127.0f), 127.0f);
            }
            const int colb = (wn + ni * 16 + kg * 4) * 4;  // byte col in row
            *reinterpret_cast<f32x4*>(
                lbase + lrow * 1024 + (colb ^ ((lrow & 7) << 4))) = o;
        }
        __syncthreads();
        // -- read row-linear + dense 1 KB NT wave stores (full lines) --
#pragma unroll
        for (int j = 0; j < 4; ++j) {
            const int idx = j * 512 + tid;        // 0..2047 16B-chunks
            const int r2  = idx >> 6;             // staging row 0..31
            const int c16 = idx & 63;             // 16B chunk in row
            f32x4 v = *reinterpret_cast<const f32x4*>(
                lbase + r2 * 1024 + ((c16 * 16) ^ ((r2 & 7) << 4)));
            const int grow = bm + ((r2 >> 4) * 64) + p * 16 + (r2 & 15);
            __builtin_nontemporal_store(v, reinterpret_cast<f32x4*>(
                out + ((size_t)h * MDIM + grow) * NDIM + bn + c16 * 4));
        }
        __syncthreads();
    }
}

extern "C" void kernel_launch(void* const* d_in, const int* in_sizes, int n_in,
                              void* d_out, int out_size, void* d_ws, size_t ws_size,
                              hipStream_t stream) {
    const int*   A  = (const int*)d_in[0];
    const int*   B  = (const int*)d_in[1];
    const float* sA = (const float*)d_in[2];
    const float* sB = (const float*)d_in[3];
    const float* sO = (const float*)d_in[4];
    float* out = (float*)d_out;

    unsigned char* A8T = (unsigned char*)d_ws;
    unsigned char* B8T = A8T + (size_t)HDIM * MDIM * KDIM;

    prep_relayout<<<2048, 256, 0, stream>>>(
        A, B, sO, A8T, B8T, out + (size_t)HDIM * MDIM * NDIM);

    gemm_i8_fused<<<2048, 512, 0, stream>>>(A8T, B8T, sA, sB, sO, out);
}